// Round 10
// baseline (847.019 us; speedup 1.0000x reference)
//
#include <hip/hip_runtime.h>
#include <cstdint>
#include <cstddef>
#include <cmath>

// Problem constants (match reference)
constexpr int Nn = 50000;
constexpr int Ne = 500000;
constexpr int Gg = 64;
constexpr int DIN = 128, ED = 32, H1 = 256, H2 = 128, HD = 64, NOUT = 8;

typedef __attribute__((ext_vector_type(8))) short bf16x8;
typedef __attribute__((ext_vector_type(4))) float f32x4;

__device__ __forceinline__ unsigned short f2bf(float x) {
    unsigned u = __float_as_uint(x);
    u += 0x7FFFu + ((u >> 16) & 1u);
    return (unsigned short)(u >> 16);
}
__device__ __forceinline__ float bf2f(unsigned short h) {
    return __uint_as_float(((unsigned)h) << 16);
}

// ---------------- CSR build ----------------
__global__ void count_deg_kernel(const int* __restrict__ dst, int* __restrict__ deg) {
    int e = blockIdx.x * 256 + threadIdx.x;
    if (e < Ne) atomicAdd(&deg[dst[e]], 1);
}

__global__ __launch_bounds__(1024) void scan_kernel(const int* __restrict__ deg,
                                                    int* __restrict__ row_start) {
    __shared__ int part[1024];
    int t = threadIdx.x;
    const int chunk = (Nn + 1023) / 1024;
    int lo = t * chunk;
    int hi = min(lo + chunk, Nn);
    int s = 0;
    for (int i = lo; i < hi; i++) s += deg[i];
    part[t] = s;
    __syncthreads();
    for (int off = 1; off < 1024; off <<= 1) {
        int add = (t >= off) ? part[t - off] : 0;
        __syncthreads();
        part[t] += add;
        __syncthreads();
    }
    int base = (t == 0) ? 0 : part[t - 1];
    for (int i = lo; i < hi; i++) { row_start[i] = base; base += deg[i]; }
    if (t == 0) row_start[Nn] = Ne;
}

__global__ void scatter_kernel(const int* __restrict__ dst, const int* __restrict__ row_start,
                               int* __restrict__ cursor, int* __restrict__ perm) {
    int e = blockIdx.x * 256 + threadIdx.x;
    if (e < Ne) {
        int d = dst[e];
        int p = atomicAdd(&cursor[d], 1);
        perm[row_start[d] + p] = e;
    }
}

__global__ void build_sd_kernel(const int* __restrict__ perm, const int* __restrict__ src,
                                const int* __restrict__ dst,
                                int* __restrict__ srcv, int* __restrict__ dstv) {
    int j = blockIdx.x * 256 + threadIdx.x;
    if (j < Ne) {
        int e = perm[j];
        srcv[j] = src[e];
        dstv[j] = dst[e];
    }
}

// loop_attr[i] = mean of incoming edge_attr rows (self-loop fill_value='mean')
__global__ void loop_attr_kernel(const int* __restrict__ row_start, const int* __restrict__ perm,
                                 const float* __restrict__ eattr, float* __restrict__ loop_attr) {
    int tid = blockIdx.x * 256 + threadIdx.x;
    if (tid >= Nn * 8) return;
    int i = tid >> 3, q = (tid & 7) << 2;
    int r0 = row_start[i], r1 = row_start[i + 1];
    float4 s = make_float4(0.f, 0.f, 0.f, 0.f);
    for (int j = r0; j < r1; j++) {
        int e = perm[j];
        float4 v = *(const float4*)(eattr + (size_t)e * ED + q);
        s.x += v.x; s.y += v.y; s.z += v.z; s.w += v.w;
    }
    float inv = 1.0f / fmaxf((float)(r1 - r0), 1.0f);
    *(float4*)(loop_attr + (size_t)i * ED + q) =
        make_float4(s.x * inv, s.y * inv, s.z * inv, s.w * inv);
}

// ---------------- batched weight transpose+split: all 6 weights in ONE dispatch ----------
__global__ void cvt_wt6_kernel(
    const float* __restrict__ We1, unsigned short* __restrict__ w1hi, unsigned short* __restrict__ w1lo,
    const float* __restrict__ We2, unsigned short* __restrict__ w2hi, unsigned short* __restrict__ w2lo,
    const float* __restrict__ Wl1, unsigned short* __restrict__ wl1hi, unsigned short* __restrict__ wl1lo,
    const float* __restrict__ Wr1, unsigned short* __restrict__ wr1hi, unsigned short* __restrict__ wr1lo,
    const float* __restrict__ Wl2, unsigned short* __restrict__ wl2hi, unsigned short* __restrict__ wl2lo,
    const float* __restrict__ Wr2, unsigned short* __restrict__ wr2hi, unsigned short* __restrict__ wr2lo) {
    const float* W; unsigned short *hi, *lo; int K, N;
    switch (blockIdx.y) {
        case 0: W = We1; hi = w1hi;  lo = w1lo;  K = ED;  N = H1; break;
        case 1: W = We2; hi = w2hi;  lo = w2lo;  K = ED;  N = H2; break;
        case 2: W = Wl1; hi = wl1hi; lo = wl1lo; K = DIN; N = H1; break;
        case 3: W = Wr1; hi = wr1hi; lo = wr1lo; K = DIN; N = H1; break;
        case 4: W = Wl2; hi = wl2hi; lo = wl2lo; K = H1;  N = H2; break;
        default: W = Wr2; hi = wr2hi; lo = wr2lo; K = H1;  N = H2; break;
    }
    int t = blockIdx.x * 256 + threadIdx.x;
    if (t >= K * N) return;
    int col = t / K, k = t % K;
    float x = W[(size_t)k * N + col];
    unsigned short h = f2bf(x);
    hi[t] = h;
    lo[t] = f2bf(x - bf2f(h));
}

// ---------------- MFMA dense GEMM v2 (R8, passing: kept byte-identical) ------------------
template <int K, int N>
__global__ __launch_bounds__(256) void gemm_mfma_kernel(
    int M, const float* __restrict__ A,
    const unsigned short* __restrict__ wt0hi, const unsigned short* __restrict__ wt0lo,
    const float* __restrict__ bias0, float* __restrict__ C0,
    const unsigned short* __restrict__ wt1hi, const unsigned short* __restrict__ wt1lo,
    const float* __restrict__ bias1, float* __restrict__ C1) {
    const unsigned short* wthi = blockIdx.z ? wt1hi : wt0hi;
    const unsigned short* wtlo = blockIdx.z ? wt1lo : wt0lo;
    const float* bias = blockIdx.z ? bias1 : bias0;
    float* Cc = blockIdx.z ? C1 : C0;
    constexpr int KC = (K > 128) ? 128 : K;   // k-chunk staged in LDS
    constexpr int P = KC + 8;                 // LDS pitch (ushorts), rows 16B-aligned
    constexpr int NT = N / 64;                // n-tiles per wave (4 waves cover N)
    constexpr int CH = KC / 4;                // float4 chunks per row per k-chunk
    __shared__ unsigned short Ah[64 * P], Al[64 * P];
    const int tid = threadIdx.x;
    const int m0 = blockIdx.y * 64;

    const int wv = tid >> 6, lane = tid & 63;
    const int g = lane >> 4, li = lane & 15;
    const int nb = wv * (N / 4);              // this wave's col base

    f32x4 acc[4][NT];
#pragma unroll
    for (int n = 0; n < NT; n++) {
        float bc = bias[nb + n * 16 + li];
#pragma unroll
        for (int m = 0; m < 4; m++) {
            acc[m][n][0] = bc; acc[m][n][1] = bc; acc[m][n][2] = bc; acc[m][n][3] = bc;
        }
    }

    for (int kc = 0; kc < K; kc += KC) {
        // stage A k-chunk: 64 node rows x KC fp32 -> hi/lo bf16 in LDS (split in-flight)
        for (int t = tid; t < 64 * CH; t += 256) {
            int row = t / CH, c = t % CH;
            int gr = min(m0 + row, M - 1);
            float4 v = *(const float4*)(A + (size_t)gr * K + kc + c * 4);
            unsigned short h0 = f2bf(v.x), h1 = f2bf(v.y), h2 = f2bf(v.z), h3 = f2bf(v.w);
            unsigned short l0 = f2bf(v.x - bf2f(h0)), l1 = f2bf(v.y - bf2f(h1));
            unsigned short l2 = f2bf(v.z - bf2f(h2)), l3 = f2bf(v.w - bf2f(h3));
            *(ushort4*)&Ah[row * P + c * 4] = make_ushort4(h0, h1, h2, h3);
            *(ushort4*)&Al[row * P + c * 4] = make_ushort4(l0, l1, l2, l3);
        }
        __syncthreads();

#pragma unroll
        for (int kt = 0; kt < KC / 32; kt++) {
            bf16x8 afh[4], afl[4], bfh[NT], bfl[NT];
#pragma unroll
            for (int m = 0; m < 4; m++) {
                afh[m] = *(const bf16x8*)&Ah[(m * 16 + li) * P + kt * 32 + g * 8];
                afl[m] = *(const bf16x8*)&Al[(m * 16 + li) * P + kt * 32 + g * 8];
            }
#pragma unroll
            for (int n = 0; n < NT; n++) {
                int col = nb + n * 16 + li;
                bfh[n] = *(const bf16x8*)(wthi + (size_t)col * K + kc + kt * 32 + g * 8);
                bfl[n] = *(const bf16x8*)(wtlo + (size_t)col * K + kc + kt * 32 + g * 8);
            }
#pragma unroll
            for (int m = 0; m < 4; m++)
#pragma unroll
                for (int n = 0; n < NT; n++) {
                    acc[m][n] = __builtin_amdgcn_mfma_f32_16x16x32_bf16(afh[m], bfh[n], acc[m][n], 0, 0, 0);
                    acc[m][n] = __builtin_amdgcn_mfma_f32_16x16x32_bf16(afh[m], bfl[n], acc[m][n], 0, 0, 0);
                    acc[m][n] = __builtin_amdgcn_mfma_f32_16x16x32_bf16(afl[m], bfh[n], acc[m][n], 0, 0, 0);
                }
        }
        __syncthreads();
    }

    // coalesced dword stores: per (m,n,r) instr, 4 node rows x 16 consecutive cols
#pragma unroll
    for (int m = 0; m < 4; m++)
#pragma unroll
        for (int n = 0; n < NT; n++) {
            int col = nb + n * 16 + li;
#pragma unroll
            for (int r = 0; r < 4; r++) {
                int node = m0 + m * 16 + g * 4 + r;
                if (node < M) Cc[(size_t)node * N + col] = acc[m][n][r];
            }
        }
}

// ---------------- MFMA score kernel v5: coalesced LDS-staged xs gathers -------------------
// R18 theory: v2/v3/v4 all ~115-128us vs 56us FETCH floor because the per-lane xl/xr
// gathers are SCATTERED 16B requests (16 lanes -> 16 different rows per instr): 4x the
// necessary L2/L3 request count, saturating the request pipe (why ILP in v3 was neutral).
// v5: 32 edges/block; xs = xl[src]+xr[dst] staged into LDS COOPERATIVELY -- each row
// loaded by C/4 consecutive threads (full 64B lines, coalesced). MFMA C-preload then
// reads xs from LDS (pitch C+4 -> rows r,r+8 share banks = 2-way = free per m136).
// Math bit-identical to v4 (same fp32 sum, same hi/lo 3-MFMA). Scattered reads left:
// 32 srcv/dstv scalars/block. LDS 39KB (C=256) -> 4 blocks/CU. No software pipeline
// (proven neutral in R6). Tripwire: WRITE ~2.1MB; >>that = spill.
template <int C>
__global__ __launch_bounds__((C / 64) * 64) void score_mfma5_kernel(
    int ecount, int eblocks, const int* __restrict__ perm,
    const int* __restrict__ srcv, const int* __restrict__ dstv,
    const float* __restrict__ eattr, float* __restrict__ esc,
    int ncount, const float* __restrict__ lattr, float* __restrict__ nsc,
    const float* __restrict__ xl, const float* __restrict__ xr,
    const unsigned short* __restrict__ wthi, const unsigned short* __restrict__ wtlo,
    const float* __restrict__ att) {
    constexpr int WPB = C / 64;          // waves per block (4 for C=256, 2 for C=128)
    constexpr int NTHR = WPB * 64;
    constexpr int EB = 32;               // edges per block
    constexpr int XP = C + 4;            // xs pitch (floats): 2-way bank aliasing, 16B-aligned
    constexpr int TPR = C / 4;           // threads per row for xs staging
    __shared__ float xs[EB * XP];
    __shared__ unsigned short Ah[EB * 40], Al[EB * 40];
    __shared__ float pw[WPB][EB];
    const int tid = threadIdx.x;
    const bool selfp = (int)blockIdx.x >= eblocks;
    const int bid = selfp ? ((int)blockIdx.x - eblocks) : (int)blockIdx.x;
    const int count = selfp ? ncount : ecount;
    const float* attr = selfp ? lattr : eattr;
    float* sc_out = selfp ? nsc : esc;
    const int j0 = bid * EB;

    // stage eattr: EB rows x 32 k fp32 -> hi/lo bf16 (split in-flight)
    for (int t = tid; t < EB * 8; t += NTHR) {
        int row = t >> 3, c = t & 7;
        int j = min(j0 + row, count - 1);
        int e = selfp ? j : perm[j];
        float4 v = *(const float4*)(attr + (size_t)e * ED + c * 4);
        unsigned short h0 = f2bf(v.x), h1 = f2bf(v.y), h2 = f2bf(v.z), h3 = f2bf(v.w);
        unsigned short l0 = f2bf(v.x - bf2f(h0)), l1 = f2bf(v.y - bf2f(h1));
        unsigned short l2 = f2bf(v.z - bf2f(h2)), l3 = f2bf(v.w - bf2f(h3));
        *(ushort4*)&Ah[row * 40 + c * 4] = make_ushort4(h0, h1, h2, h3);
        *(ushort4*)&Al[row * 40 + c * 4] = make_ushort4(l0, l1, l2, l3);
    }
    // stage xs = xl[src] + xr[dst], coalesced: TPR consecutive threads per row
    for (int u = tid; u < EB * TPR; u += NTHR) {
        int row = u / TPR, c4 = u % TPR;
        int j = min(j0 + row, count - 1);
        int s, d;
        if (selfp) { s = j; d = j; } else { s = srcv[j]; d = dstv[j]; }
        float4 a = *(const float4*)(xl + (size_t)s * C + c4 * 4);
        float4 b = *(const float4*)(xr + (size_t)d * C + c4 * 4);
        *(float4*)&xs[row * XP + c4 * 4] =
            make_float4(a.x + b.x, a.y + b.y, a.z + b.z, a.w + b.w);
    }
    __syncthreads();

    const int wv = tid >> 6, lane = tid & 63;
    const int g = lane >> 4, li = lane & 15;
    const int cb = wv * 64 + g * 4;      // lane's col base (plus m*16)

    // A operand: Wt column fragments, straight from global (tiny, L1-hot)
    bf16x8 af_h[4], af_l[4];
#pragma unroll
    for (int m = 0; m < 4; m++) {
        int col = wv * 64 + m * 16 + li;
        af_h[m] = *(const bf16x8*)(wthi + (size_t)col * ED + g * 8);
        af_l[m] = *(const bf16x8*)(wtlo + (size_t)col * ED + g * 8);
    }
    float4 attv[4];
#pragma unroll
    for (int m = 0; m < 4; m++) attv[m] = *(const float4*)(att + cb + m * 16);

#pragma unroll
    for (int n = 0; n < EB / 16; n++) {
        // B operand: this lane's edge row (edge = j0 + n*16 + li), k-slice g, from LDS
        bf16x8 bh = *(const bf16x8*)&Ah[(n * 16 + li) * 40 + g * 8];
        bf16x8 bl = *(const bf16x8*)&Al[(n * 16 + li) * 40 + g * 8];
        // acc preload from LDS xs (2-way bank = free)
        f32x4 acc[4];
#pragma unroll
        for (int m = 0; m < 4; m++) {
            float4 v = *(const float4*)&xs[(n * 16 + li) * XP + cb + m * 16];
            acc[m][0] = v.x; acc[m][1] = v.y; acc[m][2] = v.z; acc[m][3] = v.w;
        }
#pragma unroll
        for (int m = 0; m < 4; m++) {
            acc[m] = __builtin_amdgcn_mfma_f32_16x16x32_bf16(af_h[m], bh, acc[m], 0, 0, 0);
            acc[m] = __builtin_amdgcn_mfma_f32_16x16x32_bf16(af_h[m], bl, acc[m], 0, 0, 0);
            acc[m] = __builtin_amdgcn_mfma_f32_16x16x32_bf16(af_l[m], bh, acc[m], 0, 0, 0);
        }
        float s = 0.f;
#pragma unroll
        for (int m = 0; m < 4; m++) {
            const float av[4] = {attv[m].x, attv[m].y, attv[m].z, attv[m].w};
#pragma unroll
            for (int r = 0; r < 4; r++) {
                float z = acc[m][r];
                z = z > 0.f ? z : 0.2f * z;
                s = fmaf(z, av[r], s);
            }
        }
        s += __shfl_xor(s, 16);
        s += __shfl_xor(s, 32);
        if (lane < 16) pw[wv][n * 16 + li] = s;
    }

    __syncthreads();
    if (tid < EB) {
        float s = pw[0][tid];
#pragma unroll
        for (int w = 1; w < WPB; w++) s += pw[w][tid];
        int j = j0 + tid;
        if (j < count) sc_out[j] = s;
    }
}

// ---------------- aggregate: softmax over precomputed scores + pipelined gather ----------
template <int C>
__global__ __launch_bounds__(256) void aggregate2_kernel(
    const int* __restrict__ row_start, const int* __restrict__ srcv,
    const float* __restrict__ scores, const float* __restrict__ sscore,
    const float* __restrict__ xl, const float* __restrict__ bias,
    float* __restrict__ xout) {
    constexpr int VP = C / 64;
    const int wave = threadIdx.x >> 6, lane = threadIdx.x & 63;
    const int i = blockIdx.x * 4 + wave;
    if (i >= Nn) return;
    const int r0 = row_start[i], r1 = row_start[i + 1];

    // max over incoming + self
    float mx = sscore[i];
    for (int j = r0 + lane; j < r1; j += 64) mx = fmaxf(mx, scores[j]);
#pragma unroll
    for (int off = 32; off >= 1; off >>= 1) mx = fmaxf(mx, __shfl_xor(mx, off));

    float l = 0.f;
    float acc[VP];
#pragma unroll
    for (int j = 0; j < VP; j++) acc[j] = 0.f;

    float wA[4], xA[4][VP];
    auto load_batch = [&](int j0, float* w, float (*x)[VP]) {
#pragma unroll
        for (int q = 0; q < 4; q++) {
            int j = min(j0 + q, r1 - 1);
            w[q] = scores[j];
            const float* p = xl + (size_t)srcv[j] * C + lane * VP;
            if constexpr (VP == 4) {
                float4 v = *(const float4*)p;
                x[q][0] = v.x; x[q][1] = v.y; x[q][2] = v.z; x[q][3] = v.w;
            } else {
                float2 v = *(const float2*)p;
                x[q][0] = v.x; x[q][1] = v.y;
            }
        }
    };
    if (r0 < r1) load_batch(r0, wA, xA);

    for (int j0 = r0; j0 < r1; j0 += 4) {
        float wB[4], xB[4][VP];
        if (j0 + 4 < r1) load_batch(j0 + 4, wB, xB);  // prefetch next batch
        const int nb = min(4, r1 - j0);
        for (int q = 0; q < nb; q++) {
            float w = __expf(wA[q] - mx);
            l += w;
#pragma unroll
            for (int j = 0; j < VP; j++) acc[j] = fmaf(w, xA[q][j], acc[j]);
        }
        if (j0 + 4 < r1) {
#pragma unroll
            for (int q = 0; q < 4; q++) {
                wA[q] = wB[q];
#pragma unroll
                for (int j = 0; j < VP; j++) xA[q][j] = xB[q][j];
            }
        }
    }

    // self-loop
    {
        float w = __expf(sscore[i] - mx);
        l += w;
        const float* p = xl + (size_t)i * C + lane * VP;
        if constexpr (VP == 4) {
            float4 v = *(const float4*)p;
            acc[0] = fmaf(w, v.x, acc[0]); acc[1] = fmaf(w, v.y, acc[1]);
            acc[2] = fmaf(w, v.z, acc[2]); acc[3] = fmaf(w, v.w, acc[3]);
        } else {
            float2 v = *(const float2*)p;
            acc[0] = fmaf(w, v.x, acc[0]); acc[1] = fmaf(w, v.y, acc[1]);
        }
    }

    float invl = 1.0f / l;
    float* xo = xout + (size_t)i * C + lane * VP;
    if constexpr (VP == 4) {
        float4 bv = *(const float4*)(bias + lane * 4);
        float4 o;
        o.x = fmaxf(fmaf(acc[0], invl, bv.x), 0.f);
        o.y = fmaxf(fmaf(acc[1], invl, bv.y), 0.f);
        o.z = fmaxf(fmaf(acc[2], invl, bv.z), 0.f);
        o.w = fmaxf(fmaf(acc[3], invl, bv.w), 0.f);
        *(float4*)xo = o;
    } else {
        float2 bv = *(const float2*)(bias + lane * 2);
        float2 o;
        o.x = fmaxf(fmaf(acc[0], invl, bv.x), 0.f);
        o.y = fmaxf(fmaf(acc[1], invl, bv.y), 0.f);
        *(float2*)xo = o;
    }
}

// ---------------- global mean pool: run-length accumulation (batch is sorted) -------------
__global__ __launch_bounds__(128) void pool2_kernel(const float* __restrict__ x2,
                                                    const int* __restrict__ batch,
                                                    float* __restrict__ pooled,
                                                    float* __restrict__ cnt) {
    const int c = threadIdx.x;  // column 0..127
    const int chunk = (Nn + gridDim.x - 1) / gridDim.x;
    int lo = blockIdx.x * chunk;
    int hi = min(lo + chunk, Nn);
    if (lo >= hi) return;
    int gcur = batch[lo];
    float acc = 0.f, ncnt = 0.f;
    for (int i = lo; i < hi; i++) {
        int g = batch[i];
        if (g != gcur) {
            atomicAdd(&pooled[gcur * H2 + c], acc);
            if (c == 0) atomicAdd(&cnt[gcur], ncnt);
            acc = 0.f; ncnt = 0.f; gcur = g;
        }
        acc += x2[(size_t)i * H2 + c];
        ncnt += 1.f;
    }
    atomicAdd(&pooled[gcur * H2 + c], acc);
    if (c == 0) atomicAdd(&cnt[gcur], ncnt);
}

// ---------------- MLP head ----------------
__global__ __launch_bounds__(64) void head_kernel(
    const float* __restrict__ pooled, const float* __restrict__ cnt,
    const float* __restrict__ Wd1, const float* __restrict__ bd1,
    const float* __restrict__ gamma, const float* __restrict__ beta,
    const float* __restrict__ mean, const float* __restrict__ var,
    const float* __restrict__ Wd2, const float* __restrict__ bd2,
    float* __restrict__ out) {
    __shared__ float xm[H2];
    __shared__ float h[HD];
    int g = blockIdx.x, t = threadIdx.x;
    float c = fmaxf(cnt[g], 1.0f);
    for (int i = t; i < H2; i += 64) xm[i] = pooled[g * H2 + i] / c;
    __syncthreads();
    float a = bd1[t];
    for (int k = 0; k < H2; k++) a = fmaf(xm[k], Wd1[k * HD + t], a);
    a = (a - mean[t]) / sqrtf(var[t] + 1e-5f) * gamma[t] + beta[t];
    a = a > 0.f ? a : 0.1f * a;
    h[t] = a;
    __syncthreads();
    if (t < NOUT) {
        float o = bd2[t];
        for (int k = 0; k < HD; k++) o = fmaf(h[k], Wd2[k * NOUT + t], o);
        out[g * NOUT + t] = o;
    }
}

extern "C" void kernel_launch(void* const* d_in, const int* in_sizes, int n_in,
                              void* d_out, int out_size, void* d_ws, size_t ws_size,
                              hipStream_t stream) {
    const float* node_attr = (const float*)d_in[0];
    const float* edge_attr = (const float*)d_in[1];
    const int* edge_src = (const int*)d_in[2];
    const int* edge_dst = (const int*)d_in[3];
    const int* batch = (const int*)d_in[4];
    const float* Wl1 = (const float*)d_in[5];  const float* bl1 = (const float*)d_in[6];
    const float* Wr1 = (const float*)d_in[7];  const float* br1 = (const float*)d_in[8];
    const float* We1 = (const float*)d_in[9];  const float* att1 = (const float*)d_in[10];
    const float* b1 = (const float*)d_in[11];
    const float* Wl2 = (const float*)d_in[12]; const float* bl2 = (const float*)d_in[13];
    const float* Wr2 = (const float*)d_in[14]; const float* br2 = (const float*)d_in[15];
    const float* We2 = (const float*)d_in[16]; const float* att2 = (const float*)d_in[17];
    const float* b2 = (const float*)d_in[18];
    const float* Wd1 = (const float*)d_in[19]; const float* bd1 = (const float*)d_in[20];
    const float* bn_gamma = (const float*)d_in[21]; const float* bn_beta = (const float*)d_in[22];
    const float* bn_mean = (const float*)d_in[23];  const float* bn_var = (const float*)d_in[24];
    const float* Wd2 = (const float*)d_in[25]; const float* bd2 = (const float*)d_in[26];
    float* out = (float*)d_out;

    char* ws = (char*)d_ws;
    size_t off = 0;
    auto alloc = [&](size_t bytes) -> char* {
        char* p = ws + off;
        off = (off + bytes + 255) & ~(size_t)255;
        return p;
    };
    int* deg         = (int*)alloc((size_t)Nn * 4);
    int* row_start   = (int*)alloc((size_t)(Nn + 1) * 4);
    int* cursor      = (int*)alloc((size_t)Nn * 4);
    int* perm        = (int*)alloc((size_t)Ne * 4);
    int* srcv        = (int*)alloc((size_t)Ne * 4);
    int* dstv        = (int*)alloc((size_t)Ne * 4);
    float* loop_attr = (float*)alloc((size_t)Nn * ED * 4);
    float* scores    = (float*)alloc((size_t)Ne * 4);
    float* sscore    = (float*)alloc((size_t)Nn * 4);
    float* pooled    = (float*)alloc((size_t)Gg * H2 * 4);
    float* cnt       = (float*)alloc((size_t)Gg * 4);
    float* xlb       = (float*)alloc((size_t)Nn * H1 * 4);
    float* xrb       = (float*)alloc((size_t)Nn * H1 * 4);
    float* x1        = (float*)alloc((size_t)Nn * H1 * 4);
    // weight splits (all tiny; activations + edge attrs split in-kernel now)
    unsigned short* w1hi = (unsigned short*)alloc((size_t)H1 * ED * 2);
    unsigned short* w1lo = (unsigned short*)alloc((size_t)H1 * ED * 2);
    unsigned short* w2hi = (unsigned short*)alloc((size_t)H2 * ED * 2);
    unsigned short* w2lo = (unsigned short*)alloc((size_t)H2 * ED * 2);
    unsigned short* wl1hi = (unsigned short*)alloc((size_t)H1 * DIN * 2);
    unsigned short* wl1lo = (unsigned short*)alloc((size_t)H1 * DIN * 2);
    unsigned short* wr1hi = (unsigned short*)alloc((size_t)H1 * DIN * 2);
    unsigned short* wr1lo = (unsigned short*)alloc((size_t)H1 * DIN * 2);
    unsigned short* wl2hi = (unsigned short*)alloc((size_t)H2 * H1 * 2);
    unsigned short* wl2lo = (unsigned short*)alloc((size_t)H2 * H1 * 2);
    unsigned short* wr2hi = (unsigned short*)alloc((size_t)H2 * H1 * 2);
    unsigned short* wr2lo = (unsigned short*)alloc((size_t)H2 * H1 * 2);

    hipMemsetAsync(deg, 0, (size_t)Nn * 4, stream);
    hipMemsetAsync(cursor, 0, (size_t)Nn * 4, stream);
    hipMemsetAsync(pooled, 0, (size_t)Gg * H2 * 4, stream);
    hipMemsetAsync(cnt, 0, (size_t)Gg * 4, stream);

    count_deg_kernel<<<(Ne + 255) / 256, 256, 0, stream>>>(edge_dst, deg);
    scan_kernel<<<1, 1024, 0, stream>>>(deg, row_start);
    scatter_kernel<<<(Ne + 255) / 256, 256, 0, stream>>>(edge_dst, row_start, cursor, perm);
    build_sd_kernel<<<(Ne + 255) / 256, 256, 0, stream>>>(perm, edge_src, edge_dst, srcv, dstv);
    loop_attr_kernel<<<(Nn * 8 + 255) / 256, 256, 0, stream>>>(row_start, perm, edge_attr, loop_attr);

    // all 6 weight transposes+splits in one dispatch
    cvt_wt6_kernel<<<dim3((DIN * H1 + 255) / 256, 6), 256, 0, stream>>>(
        We1, w1hi, w1lo, We2, w2hi, w2lo, Wl1, wl1hi, wl1lo,
        Wr1, wr1hi, wr1lo, Wl2, wl2hi, wl2lo, Wr2, wr2hi, wr2lo);

    const int eb32 = (Ne + 31) / 32, nb32 = (Nn + 31) / 32;
    const int gb = (Nn + 63) / 64;

    // ---- layer 1 ----
    gemm_mfma_kernel<DIN, H1><<<dim3(1, gb, 2), 256, 0, stream>>>(
        Nn, node_attr, wl1hi, wl1lo, bl1, xlb, wr1hi, wr1lo, br1, xrb);
    score_mfma5_kernel<H1><<<eb32 + nb32, 256, 0, stream>>>(
        Ne, eb32, perm, srcv, dstv, edge_attr, scores,
        Nn, loop_attr, sscore, xlb, xrb, w1hi, w1lo, att1);
    aggregate2_kernel<H1><<<(Nn + 3) / 4, 256, 0, stream>>>(
        row_start, srcv, scores, sscore, xlb, b1, x1);

    // ---- layer 2 ----
    gemm_mfma_kernel<H1, H2><<<dim3(1, gb, 2), 256, 0, stream>>>(
        Nn, x1, wl2hi, wl2lo, bl2, xlb, wr2hi, wr2lo, br2, xrb);
    score_mfma5_kernel<H2><<<eb32 + nb32, 128, 0, stream>>>(
        Ne, eb32, perm, srcv, dstv, edge_attr, scores,
        Nn, loop_attr, sscore, xlb, xrb, w2hi, w2lo, att2);
    float* x2 = x1;
    aggregate2_kernel<H2><<<(Nn + 3) / 4, 256, 0, stream>>>(
        row_start, srcv, scores, sscore, xlb, b2, x2);

    // ---- pool + head ----
    pool2_kernel<<<256, 128, 0, stream>>>(x2, batch, pooled, cnt);
    head_kernel<<<Gg, 64, 0, stream>>>(pooled, cnt, Wd1, bd1, bn_gamma, bn_beta,
                                       bn_mean, bn_var, Wd2, bd2, out);
}

// Round 11
// 786.640 us; speedup vs baseline: 1.0768x; 1.0768x over previous
//
#include <hip/hip_runtime.h>
#include <cstdint>
#include <cstddef>
#include <cmath>

// Problem constants (match reference)
constexpr int Nn = 50000;
constexpr int Ne = 500000;
constexpr int Gg = 64;
constexpr int DIN = 128, ED = 32, H1 = 256, H2 = 128, HD = 64, NOUT = 8;

typedef __attribute__((ext_vector_type(8))) short bf16x8;
typedef __attribute__((ext_vector_type(4))) float f32x4;

__device__ __forceinline__ unsigned short f2bf(float x) {
    unsigned u = __float_as_uint(x);
    u += 0x7FFFu + ((u >> 16) & 1u);
    return (unsigned short)(u >> 16);
}
__device__ __forceinline__ float bf2f(unsigned short h) {
    return __uint_as_float(((unsigned)h) << 16);
}

// ---------------- CSR build ----------------
__global__ void count_deg_kernel(const int* __restrict__ dst, int* __restrict__ deg) {
    int e = blockIdx.x * 256 + threadIdx.x;
    if (e < Ne) atomicAdd(&deg[dst[e]], 1);
}

__global__ __launch_bounds__(1024) void scan_kernel(const int* __restrict__ deg,
                                                    int* __restrict__ row_start) {
    __shared__ int part[1024];
    int t = threadIdx.x;
    const int chunk = (Nn + 1023) / 1024;
    int lo = t * chunk;
    int hi = min(lo + chunk, Nn);
    int s = 0;
    for (int i = lo; i < hi; i++) s += deg[i];
    part[t] = s;
    __syncthreads();
    for (int off = 1; off < 1024; off <<= 1) {
        int add = (t >= off) ? part[t - off] : 0;
        __syncthreads();
        part[t] += add;
        __syncthreads();
    }
    int base = (t == 0) ? 0 : part[t - 1];
    for (int i = lo; i < hi; i++) { row_start[i] = base; base += deg[i]; }
    if (t == 0) row_start[Nn] = Ne;
}

// R19: build_sd merged into scatter (scatter already holds e, d, and slot j) -> one fewer
// 500k-thread dispatch + no re-read of perm/src/dst (~10MB saved).
__global__ void scatter_kernel(const int* __restrict__ src, const int* __restrict__ dst,
                               const int* __restrict__ row_start,
                               int* __restrict__ cursor, int* __restrict__ perm,
                               int* __restrict__ srcv, int* __restrict__ dstv) {
    int e = blockIdx.x * 256 + threadIdx.x;
    if (e < Ne) {
        int d = dst[e];
        int p = atomicAdd(&cursor[d], 1);
        int j = row_start[d] + p;
        perm[j] = e;
        srcv[j] = src[e];
        dstv[j] = d;
    }
}

// loop_attr[i] = mean of incoming edge_attr rows (self-loop fill_value='mean')
__global__ void loop_attr_kernel(const int* __restrict__ row_start, const int* __restrict__ perm,
                                 const float* __restrict__ eattr, float* __restrict__ loop_attr) {
    int tid = blockIdx.x * 256 + threadIdx.x;
    if (tid >= Nn * 8) return;
    int i = tid >> 3, q = (tid & 7) << 2;
    int r0 = row_start[i], r1 = row_start[i + 1];
    float4 s = make_float4(0.f, 0.f, 0.f, 0.f);
    for (int j = r0; j < r1; j++) {
        int e = perm[j];
        float4 v = *(const float4*)(eattr + (size_t)e * ED + q);
        s.x += v.x; s.y += v.y; s.z += v.z; s.w += v.w;
    }
    float inv = 1.0f / fmaxf((float)(r1 - r0), 1.0f);
    *(float4*)(loop_attr + (size_t)i * ED + q) =
        make_float4(s.x * inv, s.y * inv, s.z * inv, s.w * inv);
}

// ---------------- batched weight transpose+split: all 6 weights in ONE dispatch ----------
__global__ void cvt_wt6_kernel(
    const float* __restrict__ We1, unsigned short* __restrict__ w1hi, unsigned short* __restrict__ w1lo,
    const float* __restrict__ We2, unsigned short* __restrict__ w2hi, unsigned short* __restrict__ w2lo,
    const float* __restrict__ Wl1, unsigned short* __restrict__ wl1hi, unsigned short* __restrict__ wl1lo,
    const float* __restrict__ Wr1, unsigned short* __restrict__ wr1hi, unsigned short* __restrict__ wr1lo,
    const float* __restrict__ Wl2, unsigned short* __restrict__ wl2hi, unsigned short* __restrict__ wl2lo,
    const float* __restrict__ Wr2, unsigned short* __restrict__ wr2hi, unsigned short* __restrict__ wr2lo) {
    const float* W; unsigned short *hi, *lo; int K, N;
    switch (blockIdx.y) {
        case 0: W = We1; hi = w1hi;  lo = w1lo;  K = ED;  N = H1; break;
        case 1: W = We2; hi = w2hi;  lo = w2lo;  K = ED;  N = H2; break;
        case 2: W = Wl1; hi = wl1hi; lo = wl1lo; K = DIN; N = H1; break;
        case 3: W = Wr1; hi = wr1hi; lo = wr1lo; K = DIN; N = H1; break;
        case 4: W = Wl2; hi = wl2hi; lo = wl2lo; K = H1;  N = H2; break;
        default: W = Wr2; hi = wr2hi; lo = wr2lo; K = H1;  N = H2; break;
    }
    int t = blockIdx.x * 256 + threadIdx.x;
    if (t >= K * N) return;
    int col = t / K, k = t % K;
    float x = W[(size_t)k * N + col];
    unsigned short h = f2bf(x);
    hi[t] = h;
    lo[t] = f2bf(x - bf2f(h));
}

// ---------------- MFMA dense GEMM v2 (R8, passing: kept byte-identical) ------------------
template <int K, int N>
__global__ __launch_bounds__(256) void gemm_mfma_kernel(
    int M, const float* __restrict__ A,
    const unsigned short* __restrict__ wt0hi, const unsigned short* __restrict__ wt0lo,
    const float* __restrict__ bias0, float* __restrict__ C0,
    const unsigned short* __restrict__ wt1hi, const unsigned short* __restrict__ wt1lo,
    const float* __restrict__ bias1, float* __restrict__ C1) {
    const unsigned short* wthi = blockIdx.z ? wt1hi : wt0hi;
    const unsigned short* wtlo = blockIdx.z ? wt1lo : wt0lo;
    const float* bias = blockIdx.z ? bias1 : bias0;
    float* Cc = blockIdx.z ? C1 : C0;
    constexpr int KC = (K > 128) ? 128 : K;   // k-chunk staged in LDS
    constexpr int P = KC + 8;                 // LDS pitch (ushorts), rows 16B-aligned
    constexpr int NT = N / 64;                // n-tiles per wave (4 waves cover N)
    constexpr int CH = KC / 4;                // float4 chunks per row per k-chunk
    __shared__ unsigned short Ah[64 * P], Al[64 * P];
    const int tid = threadIdx.x;
    const int m0 = blockIdx.y * 64;

    const int wv = tid >> 6, lane = tid & 63;
    const int g = lane >> 4, li = lane & 15;
    const int nb = wv * (N / 4);              // this wave's col base

    f32x4 acc[4][NT];
#pragma unroll
    for (int n = 0; n < NT; n++) {
        float bc = bias[nb + n * 16 + li];
#pragma unroll
        for (int m = 0; m < 4; m++) {
            acc[m][n][0] = bc; acc[m][n][1] = bc; acc[m][n][2] = bc; acc[m][n][3] = bc;
        }
    }

    for (int kc = 0; kc < K; kc += KC) {
        // stage A k-chunk: 64 node rows x KC fp32 -> hi/lo bf16 in LDS (split in-flight)
        for (int t = tid; t < 64 * CH; t += 256) {
            int row = t / CH, c = t % CH;
            int gr = min(m0 + row, M - 1);
            float4 v = *(const float4*)(A + (size_t)gr * K + kc + c * 4);
            unsigned short h0 = f2bf(v.x), h1 = f2bf(v.y), h2 = f2bf(v.z), h3 = f2bf(v.w);
            unsigned short l0 = f2bf(v.x - bf2f(h0)), l1 = f2bf(v.y - bf2f(h1));
            unsigned short l2 = f2bf(v.z - bf2f(h2)), l3 = f2bf(v.w - bf2f(h3));
            *(ushort4*)&Ah[row * P + c * 4] = make_ushort4(h0, h1, h2, h3);
            *(ushort4*)&Al[row * P + c * 4] = make_ushort4(l0, l1, l2, l3);
        }
        __syncthreads();

#pragma unroll
        for (int kt = 0; kt < KC / 32; kt++) {
            bf16x8 afh[4], afl[4], bfh[NT], bfl[NT];
#pragma unroll
            for (int m = 0; m < 4; m++) {
                afh[m] = *(const bf16x8*)&Ah[(m * 16 + li) * P + kt * 32 + g * 8];
                afl[m] = *(const bf16x8*)&Al[(m * 16 + li) * P + kt * 32 + g * 8];
            }
#pragma unroll
            for (int n = 0; n < NT; n++) {
                int col = nb + n * 16 + li;
                bfh[n] = *(const bf16x8*)(wthi + (size_t)col * K + kc + kt * 32 + g * 8);
                bfl[n] = *(const bf16x8*)(wtlo + (size_t)col * K + kc + kt * 32 + g * 8);
            }
#pragma unroll
            for (int m = 0; m < 4; m++)
#pragma unroll
                for (int n = 0; n < NT; n++) {
                    acc[m][n] = __builtin_amdgcn_mfma_f32_16x16x32_bf16(afh[m], bfh[n], acc[m][n], 0, 0, 0);
                    acc[m][n] = __builtin_amdgcn_mfma_f32_16x16x32_bf16(afh[m], bfl[n], acc[m][n], 0, 0, 0);
                    acc[m][n] = __builtin_amdgcn_mfma_f32_16x16x32_bf16(afl[m], bfh[n], acc[m][n], 0, 0, 0);
                }
        }
        __syncthreads();
    }

    // coalesced dword stores: per (m,n,r) instr, 4 node rows x 16 consecutive cols
#pragma unroll
    for (int m = 0; m < 4; m++)
#pragma unroll
        for (int n = 0; n < NT; n++) {
            int col = nb + n * 16 + li;
#pragma unroll
            for (int r = 0; r < 4; r++) {
                int node = m0 + m * 16 + g * 4 + r;
                if (node < M) Cc[(size_t)node * N + col] = acc[m][n][r];
            }
        }
}

// ---------------- MFMA score kernel v4 (R9-proven, 128us; PARKED) ------------------------
// R10 lesson: v5's coalesced-LDS-staging regressed (169us) -- serialized gather latency
// behind one barrier and lost wave-level overlap. v4's scattered per-lane gathers ARE the
// cache-hierarchy floor for this structure. Do not touch again.
template <int C>
__global__ __launch_bounds__((C / 64) * 64) void score_mfma4_kernel(
    int ecount, int eblocks, const int* __restrict__ perm,
    const int* __restrict__ srcv, const int* __restrict__ dstv,
    const float* __restrict__ eattr, float* __restrict__ esc,
    int ncount, const float* __restrict__ lattr, float* __restrict__ nsc,
    const float* __restrict__ xl, const float* __restrict__ xr,
    const unsigned short* __restrict__ wthi, const unsigned short* __restrict__ wtlo,
    const float* __restrict__ att) {
    constexpr int WPB = C / 64;          // waves per block (4 for C=256, 2 for C=128)
    constexpr int NTHR = WPB * 64;
    __shared__ unsigned short Ah[64 * 40], Al[64 * 40];  // pitch 40 ush = 80B, 16B-aligned
    __shared__ float pw[WPB][64];
    const int tid = threadIdx.x;
    const bool selfp = (int)blockIdx.x >= eblocks;
    const int bid = selfp ? ((int)blockIdx.x - eblocks) : (int)blockIdx.x;
    const int count = selfp ? ncount : ecount;
    const float* attr = selfp ? lattr : eattr;
    float* sc_out = selfp ? nsc : esc;
    const int j0 = bid * 64;

    // stage 64 rows x 32 k fp32 -> hi/lo bf16 in LDS (split in-flight)
    for (int t = tid; t < 64 * 8; t += NTHR) {
        int row = t >> 3, c = t & 7;
        int j = min(j0 + row, count - 1);
        int e = selfp ? j : perm[j];
        float4 v = *(const float4*)(attr + (size_t)e * ED + c * 4);
        unsigned short h0 = f2bf(v.x), h1 = f2bf(v.y), h2 = f2bf(v.z), h3 = f2bf(v.w);
        unsigned short l0 = f2bf(v.x - bf2f(h0)), l1 = f2bf(v.y - bf2f(h1));
        unsigned short l2 = f2bf(v.z - bf2f(h2)), l3 = f2bf(v.w - bf2f(h3));
        *(ushort4*)&Ah[row * 40 + c * 4] = make_ushort4(h0, h1, h2, h3);
        *(ushort4*)&Al[row * 40 + c * 4] = make_ushort4(l0, l1, l2, l3);
    }
    __syncthreads();

    const int wv = tid >> 6, lane = tid & 63;
    const int g = lane >> 4, li = lane & 15;
    const int cb = wv * 64 + g * 4;      // lane's col base (plus m*16)

    // A operand: Wt column fragments, straight from global (tiny, L1-hot)
    bf16x8 af_h[4], af_l[4];
#pragma unroll
    for (int m = 0; m < 4; m++) {
        int col = wv * 64 + m * 16 + li;
        af_h[m] = *(const bf16x8*)(wthi + (size_t)col * ED + g * 8);
        af_l[m] = *(const bf16x8*)(wtlo + (size_t)col * ED + g * 8);
    }
    float4 attv[4];
#pragma unroll
    for (int m = 0; m < 4; m++) attv[m] = *(const float4*)(att + cb + m * 16);

    // hoisted edge indices for all 4 n-tiles (scalars, no arrays -> no scratch)
    int s0, d0, s1, d1, s2, d2, s3, d3;
    {
        int j;
        j = min(j0 + 0 * 16 + li, count - 1);
        s0 = selfp ? j : srcv[j]; d0 = selfp ? j : dstv[j];
        j = min(j0 + 1 * 16 + li, count - 1);
        s1 = selfp ? j : srcv[j]; d1 = selfp ? j : dstv[j];
        j = min(j0 + 2 * 16 + li, count - 1);
        s2 = selfp ? j : srcv[j]; d2 = selfp ? j : dstv[j];
        j = min(j0 + 3 * 16 + li, count - 1);
        s3 = selfp ? j : srcv[j]; d3 = selfp ? j : dstv[j];
    }

    // prefetch: LDS B-fragments + xl/xr gathers for one tile into a named register set
    auto pf = [&](int n, int sE, int dE, bf16x8& bh, bf16x8& bl,
                  float4 (&xlv)[4], float4 (&xrv)[4]) {
        bh = *(const bf16x8*)&Ah[(n * 16 + li) * 40 + g * 8];
        bl = *(const bf16x8*)&Al[(n * 16 + li) * 40 + g * 8];
        const float* pl = xl + (size_t)sE * C + cb;
        const float* pr = xr + (size_t)dE * C + cb;
#pragma unroll
        for (int m = 0; m < 4; m++) {
            xlv[m] = *(const float4*)(pl + m * 16);
            xrv[m] = *(const float4*)(pr + m * 16);
        }
    };
    // compute: acc preload (C-op = xl+xr), 12 MFMAs, LReLU+att-dot epilogue, partial write
    auto comp = [&](int n, bf16x8 bh, bf16x8 bl,
                    const float4 (&xlv)[4], const float4 (&xrv)[4]) {
        f32x4 acc[4];
#pragma unroll
        for (int m = 0; m < 4; m++) {
            acc[m][0] = xlv[m].x + xrv[m].x; acc[m][1] = xlv[m].y + xrv[m].y;
            acc[m][2] = xlv[m].z + xrv[m].z; acc[m][3] = xlv[m].w + xrv[m].w;
        }
#pragma unroll
        for (int m = 0; m < 4; m++) {
            acc[m] = __builtin_amdgcn_mfma_f32_16x16x32_bf16(af_h[m], bh, acc[m], 0, 0, 0);
            acc[m] = __builtin_amdgcn_mfma_f32_16x16x32_bf16(af_h[m], bl, acc[m], 0, 0, 0);
            acc[m] = __builtin_amdgcn_mfma_f32_16x16x32_bf16(af_l[m], bh, acc[m], 0, 0, 0);
        }
        float s = 0.f;
#pragma unroll
        for (int m = 0; m < 4; m++) {
            const float av[4] = {attv[m].x, attv[m].y, attv[m].z, attv[m].w};
#pragma unroll
            for (int r = 0; r < 4; r++) {
                float z = acc[m][r];
                z = z > 0.f ? z : 0.2f * z;
                s = fmaf(z, av[r], s);
            }
        }
        s += __shfl_xor(s, 16);
        s += __shfl_xor(s, 32);
        if (lane < 16) pw[wv][n * 16 + li] = s;
    };

    bf16x8 bhA, blA, bhB, blB;
    float4 xlA[4], xrA[4], xlB[4], xrB[4];
    pf(0, s0, d0, bhA, blA, xlA, xrA);
    pf(1, s1, d1, bhB, blB, xlB, xrB);
    comp(0, bhA, blA, xlA, xrA);
    pf(2, s2, d2, bhA, blA, xlA, xrA);
    comp(1, bhB, blB, xlB, xrB);
    pf(3, s3, d3, bhB, blB, xlB, xrB);
    comp(2, bhA, blA, xlA, xrA);
    comp(3, bhB, blB, xlB, xrB);

    __syncthreads();
    if (tid < 64) {
        float s = pw[0][tid];
#pragma unroll
        for (int w = 1; w < WPB; w++) s += pw[w][tid];
        int j = j0 + tid;
        if (j < count) sc_out[j] = s;
    }
}

// ---------------- aggregate: softmax over precomputed scores + pipelined gather ----------
template <int C>
__global__ __launch_bounds__(256) void aggregate2_kernel(
    const int* __restrict__ row_start, const int* __restrict__ srcv,
    const float* __restrict__ scores, const float* __restrict__ sscore,
    const float* __restrict__ xl, const float* __restrict__ bias,
    float* __restrict__ xout) {
    constexpr int VP = C / 64;
    const int wave = threadIdx.x >> 6, lane = threadIdx.x & 63;
    const int i = blockIdx.x * 4 + wave;
    if (i >= Nn) return;
    const int r0 = row_start[i], r1 = row_start[i + 1];

    // max over incoming + self
    float mx = sscore[i];
    for (int j = r0 + lane; j < r1; j += 64) mx = fmaxf(mx, scores[j]);
#pragma unroll
    for (int off = 32; off >= 1; off >>= 1) mx = fmaxf(mx, __shfl_xor(mx, off));

    float l = 0.f;
    float acc[VP];
#pragma unroll
    for (int j = 0; j < VP; j++) acc[j] = 0.f;

    float wA[4], xA[4][VP];
    auto load_batch = [&](int j0, float* w, float (*x)[VP]) {
#pragma unroll
        for (int q = 0; q < 4; q++) {
            int j = min(j0 + q, r1 - 1);
            w[q] = scores[j];
            const float* p = xl + (size_t)srcv[j] * C + lane * VP;
            if constexpr (VP == 4) {
                float4 v = *(const float4*)p;
                x[q][0] = v.x; x[q][1] = v.y; x[q][2] = v.z; x[q][3] = v.w;
            } else {
                float2 v = *(const float2*)p;
                x[q][0] = v.x; x[q][1] = v.y;
            }
        }
    };
    if (r0 < r1) load_batch(r0, wA, xA);

    for (int j0 = r0; j0 < r1; j0 += 4) {
        float wB[4], xB[4][VP];
        if (j0 + 4 < r1) load_batch(j0 + 4, wB, xB);  // prefetch next batch
        const int nb = min(4, r1 - j0);
        for (int q = 0; q < nb; q++) {
            float w = __expf(wA[q] - mx);
            l += w;
#pragma unroll
            for (int j = 0; j < VP; j++) acc[j] = fmaf(w, xA[q][j], acc[j]);
        }
        if (j0 + 4 < r1) {
#pragma unroll
            for (int q = 0; q < 4; q++) {
                wA[q] = wB[q];
#pragma unroll
                for (int j = 0; j < VP; j++) xA[q][j] = xB[q][j];
            }
        }
    }

    // self-loop
    {
        float w = __expf(sscore[i] - mx);
        l += w;
        const float* p = xl + (size_t)i * C + lane * VP;
        if constexpr (VP == 4) {
            float4 v = *(const float4*)p;
            acc[0] = fmaf(w, v.x, acc[0]); acc[1] = fmaf(w, v.y, acc[1]);
            acc[2] = fmaf(w, v.z, acc[2]); acc[3] = fmaf(w, v.w, acc[3]);
        } else {
            float2 v = *(const float2*)p;
            acc[0] = fmaf(w, v.x, acc[0]); acc[1] = fmaf(w, v.y, acc[1]);
        }
    }

    float invl = 1.0f / l;
    float* xo = xout + (size_t)i * C + lane * VP;
    if constexpr (VP == 4) {
        float4 bv = *(const float4*)(bias + lane * 4);
        float4 o;
        o.x = fmaxf(fmaf(acc[0], invl, bv.x), 0.f);
        o.y = fmaxf(fmaf(acc[1], invl, bv.y), 0.f);
        o.z = fmaxf(fmaf(acc[2], invl, bv.z), 0.f);
        o.w = fmaxf(fmaf(acc[3], invl, bv.w), 0.f);
        *(float4*)xo = o;
    } else {
        float2 bv = *(const float2*)(bias + lane * 2);
        float2 o;
        o.x = fmaxf(fmaf(acc[0], invl, bv.x), 0.f);
        o.y = fmaxf(fmaf(acc[1], invl, bv.y), 0.f);
        *(float2*)xo = o;
    }
}

// ---------------- global mean pool: run-length accumulation (batch is sorted) -------------
__global__ __launch_bounds__(128) void pool2_kernel(const float* __restrict__ x2,
                                                    const int* __restrict__ batch,
                                                    float* __restrict__ pooled,
                                                    float* __restrict__ cnt) {
    const int c = threadIdx.x;  // column 0..127
    const int chunk = (Nn + gridDim.x - 1) / gridDim.x;
    int lo = blockIdx.x * chunk;
    int hi = min(lo + chunk, Nn);
    if (lo >= hi) return;
    int gcur = batch[lo];
    float acc = 0.f, ncnt = 0.f;
    for (int i = lo; i < hi; i++) {
        int g = batch[i];
        if (g != gcur) {
            atomicAdd(&pooled[gcur * H2 + c], acc);
            if (c == 0) atomicAdd(&cnt[gcur], ncnt);
            acc = 0.f; ncnt = 0.f; gcur = g;
        }
        acc += x2[(size_t)i * H2 + c];
        ncnt += 1.f;
    }
    atomicAdd(&pooled[gcur * H2 + c], acc);
    if (c == 0) atomicAdd(&cnt[gcur], ncnt);
}

// ---------------- MLP head ----------------
__global__ __launch_bounds__(64) void head_kernel(
    const float* __restrict__ pooled, const float* __restrict__ cnt,
    const float* __restrict__ Wd1, const float* __restrict__ bd1,
    const float* __restrict__ gamma, const float* __restrict__ beta,
    const float* __restrict__ mean, const float* __restrict__ var,
    const float* __restrict__ Wd2, const float* __restrict__ bd2,
    float* __restrict__ out) {
    __shared__ float xm[H2];
    __shared__ float h[HD];
    int g = blockIdx.x, t = threadIdx.x;
    float c = fmaxf(cnt[g], 1.0f);
    for (int i = t; i < H2; i += 64) xm[i] = pooled[g * H2 + i] / c;
    __syncthreads();
    float a = bd1[t];
    for (int k = 0; k < H2; k++) a = fmaf(xm[k], Wd1[k * HD + t], a);
    a = (a - mean[t]) / sqrtf(var[t] + 1e-5f) * gamma[t] + beta[t];
    a = a > 0.f ? a : 0.1f * a;
    h[t] = a;
    __syncthreads();
    if (t < NOUT) {
        float o = bd2[t];
        for (int k = 0; k < HD; k++) o = fmaf(h[k], Wd2[k * NOUT + t], o);
        out[g * NOUT + t] = o;
    }
}

extern "C" void kernel_launch(void* const* d_in, const int* in_sizes, int n_in,
                              void* d_out, int out_size, void* d_ws, size_t ws_size,
                              hipStream_t stream) {
    const float* node_attr = (const float*)d_in[0];
    const float* edge_attr = (const float*)d_in[1];
    const int* edge_src = (const int*)d_in[2];
    const int* edge_dst = (const int*)d_in[3];
    const int* batch = (const int*)d_in[4];
    const float* Wl1 = (const float*)d_in[5];  const float* bl1 = (const float*)d_in[6];
    const float* Wr1 = (const float*)d_in[7];  const float* br1 = (const float*)d_in[8];
    const float* We1 = (const float*)d_in[9];  const float* att1 = (const float*)d_in[10];
    const float* b1 = (const float*)d_in[11];
    const float* Wl2 = (const float*)d_in[12]; const float* bl2 = (const float*)d_in[13];
    const float* Wr2 = (const float*)d_in[14]; const float* br2 = (const float*)d_in[15];
    const float* We2 = (const float*)d_in[16]; const float* att2 = (const float*)d_in[17];
    const float* b2 = (const float*)d_in[18];
    const float* Wd1 = (const float*)d_in[19]; const float* bd1 = (const float*)d_in[20];
    const float* bn_gamma = (const float*)d_in[21]; const float* bn_beta = (const float*)d_in[22];
    const float* bn_mean = (const float*)d_in[23];  const float* bn_var = (const float*)d_in[24];
    const float* Wd2 = (const float*)d_in[25]; const float* bd2 = (const float*)d_in[26];
    float* out = (float*)d_out;

    char* ws = (char*)d_ws;
    size_t off = 0;
    auto alloc = [&](size_t bytes) -> char* {
        char* p = ws + off;
        off = (off + bytes + 255) & ~(size_t)255;
        return p;
    };
    int* deg         = (int*)alloc((size_t)Nn * 4);
    int* row_start   = (int*)alloc((size_t)(Nn + 1) * 4);
    int* cursor      = (int*)alloc((size_t)Nn * 4);
    int* perm        = (int*)alloc((size_t)Ne * 4);
    int* srcv        = (int*)alloc((size_t)Ne * 4);
    int* dstv        = (int*)alloc((size_t)Ne * 4);
    float* loop_attr = (float*)alloc((size_t)Nn * ED * 4);
    float* scores    = (float*)alloc((size_t)Ne * 4);
    float* sscore    = (float*)alloc((size_t)Nn * 4);
    float* pooled    = (float*)alloc((size_t)Gg * H2 * 4);
    float* cnt       = (float*)alloc((size_t)Gg * 4);
    float* xlb       = (float*)alloc((size_t)Nn * H1 * 4);
    float* xrb       = (float*)alloc((size_t)Nn * H1 * 4);
    float* x1        = (float*)alloc((size_t)Nn * H1 * 4);
    // weight splits (all tiny; activations + edge attrs split in-kernel now)
    unsigned short* w1hi = (unsigned short*)alloc((size_t)H1 * ED * 2);
    unsigned short* w1lo = (unsigned short*)alloc((size_t)H1 * ED * 2);
    unsigned short* w2hi = (unsigned short*)alloc((size_t)H2 * ED * 2);
    unsigned short* w2lo = (unsigned short*)alloc((size_t)H2 * ED * 2);
    unsigned short* wl1hi = (unsigned short*)alloc((size_t)H1 * DIN * 2);
    unsigned short* wl1lo = (unsigned short*)alloc((size_t)H1 * DIN * 2);
    unsigned short* wr1hi = (unsigned short*)alloc((size_t)H1 * DIN * 2);
    unsigned short* wr1lo = (unsigned short*)alloc((size_t)H1 * DIN * 2);
    unsigned short* wl2hi = (unsigned short*)alloc((size_t)H2 * H1 * 2);
    unsigned short* wl2lo = (unsigned short*)alloc((size_t)H2 * H1 * 2);
    unsigned short* wr2hi = (unsigned short*)alloc((size_t)H2 * H1 * 2);
    unsigned short* wr2lo = (unsigned short*)alloc((size_t)H2 * H1 * 2);

    hipMemsetAsync(deg, 0, (size_t)Nn * 4, stream);
    hipMemsetAsync(cursor, 0, (size_t)Nn * 4, stream);
    hipMemsetAsync(pooled, 0, (size_t)Gg * H2 * 4, stream);
    hipMemsetAsync(cnt, 0, (size_t)Gg * 4, stream);

    count_deg_kernel<<<(Ne + 255) / 256, 256, 0, stream>>>(edge_dst, deg);
    scan_kernel<<<1, 1024, 0, stream>>>(deg, row_start);
    scatter_kernel<<<(Ne + 255) / 256, 256, 0, stream>>>(
        edge_src, edge_dst, row_start, cursor, perm, srcv, dstv);
    loop_attr_kernel<<<(Nn * 8 + 255) / 256, 256, 0, stream>>>(row_start, perm, edge_attr, loop_attr);

    // all 6 weight transposes+splits in one dispatch
    cvt_wt6_kernel<<<dim3((DIN * H1 + 255) / 256, 6), 256, 0, stream>>>(
        We1, w1hi, w1lo, We2, w2hi, w2lo, Wl1, wl1hi, wl1lo,
        Wr1, wr1hi, wr1lo, Wl2, wl2hi, wl2lo, Wr2, wr2hi, wr2lo);

    const int eb64 = (Ne + 63) / 64, nb64 = (Nn + 63) / 64;
    const int gb = (Nn + 63) / 64;

    // ---- layer 1 ----
    gemm_mfma_kernel<DIN, H1><<<dim3(1, gb, 2), 256, 0, stream>>>(
        Nn, node_attr, wl1hi, wl1lo, bl1, xlb, wr1hi, wr1lo, br1, xrb);
    score_mfma4_kernel<H1><<<eb64 + nb64, 256, 0, stream>>>(
        Ne, eb64, perm, srcv, dstv, edge_attr, scores,
        Nn, loop_attr, sscore, xlb, xrb, w1hi, w1lo, att1);
    aggregate2_kernel<H1><<<(Nn + 3) / 4, 256, 0, stream>>>(
        row_start, srcv, scores, sscore, xlb, b1, x1);

    // ---- layer 2 ----
    gemm_mfma_kernel<H1, H2><<<dim3(1, gb, 2), 256, 0, stream>>>(
        Nn, x1, wl2hi, wl2lo, bl2, xlb, wr2hi, wr2lo, br2, xrb);
    score_mfma4_kernel<H2><<<eb64 + nb64, 128, 0, stream>>>(
        Ne, eb64, perm, srcv, dstv, edge_attr, scores,
        Nn, loop_attr, sscore, xlb, xrb, w2hi, w2lo, att2);
    float* x2 = x1;
    aggregate2_kernel<H2><<<(Nn + 3) / 4, 256, 0, stream>>>(
        row_start, srcv, scores, sscore, xlb, b2, x2);

    // ---- pool + head ----
    pool2_kernel<<<256, 128, 0, stream>>>(x2, batch, pooled, cnt);
    head_kernel<<<Gg, 64, 0, stream>>>(pooled, cnt, Wd1, bd1, bn_gamma, bn_beta,
                                       bn_mean, bn_var, Wd2, bd2, out);
}